// Round 3
// baseline (422.672 us; speedup 1.0000x reference)
//
#include <hip/hip_runtime.h>
#include <hip/hip_fp16.h>

// HeteroGraphSage: 2-layer SAGEConv(mean) + PReLU + input-skip.
// N=100000, IN=D=64, E=1600000, fp32 in/out. Mean degree 16.
// R3: layer kernel split. The fused kernel was latency-bound (VALU 37%,
// HBM 17%, occupancy pinned at ~12 waves/CU across LDS configs). The
// gather is now a ZERO-LDS 256-thread kernel (all degree state in SGPRs,
// <=64 VGPR target) so 32 waves/CU can keep ~256 gather misses in flight;
// it writes mean-aggregated rows fp16. The dense part (3x [64x64] GEMM +
// PReLU + skip) is a separate stream-bound kernel. Padded CSR shrunk to
// 32 slots/node (Poisson-16 tail spills via ovf list).

#define BLOCK 512
#define OVF_CAP 8192
#define BSHIFT 8                    // 256 nodes per bucket
#define BCAP 8000
#define PAD 32                      // CSR slots per node

struct alignas(16) h2x4 { __half2 a, b, c, d; };

// ---- build pass 1: bin edges by dst>>8 with per-block LDS histogram.
#define P1_CHUNK 4096
__global__ __launch_bounds__(256) void bin_kernel(
    const int* __restrict__ src, const int* __restrict__ dst,
    int* __restrict__ bcnt, unsigned int* __restrict__ bucket,
    int NB, int E)
{
    __shared__ int cnt[512];
    __shared__ int base[512];
    const int tid = threadIdx.x;
    const int e0  = blockIdx.x * P1_CHUNK;

    for (int i = tid; i < NB; i += 256) cnt[i] = 0;
    __syncthreads();

    int dv[16], sv[16];
#pragma unroll
    for (int u = 0; u < 16; u++) {
        const int e = e0 + u * 256 + tid;
        if (e < E) { dv[u] = dst[e]; sv[u] = src[e]; }
        else       { dv[u] = -1; sv[u] = 0; }
    }
#pragma unroll
    for (int u = 0; u < 16; u++)
        if (dv[u] >= 0) atomicAdd(&cnt[dv[u] >> BSHIFT], 1);
    __syncthreads();

    for (int i = tid; i < NB; i += 256) {
        const int c = cnt[i];
        base[i] = (c > 0) ? atomicAdd(&bcnt[i], c) : 0;
        cnt[i]  = 0;
    }
    __syncthreads();

#pragma unroll
    for (int u = 0; u < 16; u++) {
        if (dv[u] >= 0) {
            const int b = dv[u] >> BSHIFT;
            const int r = atomicAdd(&cnt[b], 1);
            const int pos = base[b] + r;
            if (pos < BCAP)
                bucket[(size_t)b * BCAP + pos] =
                    ((unsigned int)(dv[u] & 255) << 17) | (unsigned int)sv[u];
        }
    }
}

// ---- build pass 2: one block per bucket -> padded CSR + deg.
__global__ __launch_bounds__(256) void csr_kernel(
    const int* __restrict__ bcnt, const unsigned int* __restrict__ bucket,
    int* __restrict__ deg, unsigned int* __restrict__ esort,
    unsigned long long* __restrict__ ovf, int* __restrict__ ovf_cnt, int n)
{
    __shared__ int cnt2[256];
    const int b   = blockIdx.x;
    const int tid = threadIdx.x;
    cnt2[tid] = 0;
    __syncthreads();

    const int m     = min(bcnt[b], BCAP);
    const int nbase = b << BSHIFT;
    for (int i = tid; i < m; i += 256) {
        const unsigned int e = bucket[(size_t)b * BCAP + i];
        const int dloc = (int)(e >> 17);
        const int s    = (int)(e & 0x1FFFF);
        const int r    = atomicAdd(&cnt2[dloc], 1);
        if (r < PAD) {
            esort[(size_t)(nbase + dloc) * PAD + r] = (unsigned int)s;
        } else {
            const int p = atomicAdd(ovf_cnt, 1);
            if (p < OVF_CAP)
                ovf[p] = ((unsigned long long)(unsigned int)(nbase + dloc) << 32)
                       | (unsigned long long)(unsigned int)s;
        }
    }
    __syncthreads();
    const int node = nbase + tid;
    if (node < n) deg[node] = cnt2[tid];
}

// fp32 -> fp16 table (m = count of float2 pairs)
__global__ __launch_bounds__(256) void cvt_half_kernel(
    const float2* __restrict__ in, __half2* __restrict__ out, int m)
{
    int i = blockIdx.x * blockDim.x + threadIdx.x;
    int stride = gridDim.x * blockDim.x;
    for (; i < m; i += stride) {
        float2 v = in[i];
        out[i] = __floats2half2_rn(v.x, v.y);
    }
}

static __device__ inline __half2 h2shfl_xor(__half2 v, int mask) {
    union { __half2 h; int i; } u; u.h = v;
    u.i = __shfl_xor(u.i, mask);
    return u.h;
}

// ---- Phase A standalone: mean-aggregate neighbors -> aggh (fp16).
// Zero LDS, 4 waves/block, degree state in SGPRs. Wave owns 8 nodes;
// octet layout: 8 edges per 1KB wave-load (o=edge, g=16B chunk).
__global__ __launch_bounds__(256, 6) void gather_kernel(
    const int* __restrict__ deg, const unsigned int* __restrict__ esort,
    const unsigned long long* __restrict__ ovf, const int* __restrict__ ovf_cnt,
    const __half* __restrict__ hh, __half* __restrict__ aggh, int n)
{
    const int tid  = threadIdx.x;
    const int lane = tid & 63;
    const int wvu  = tid >> 6;    // 0..3
    const int o    = lane >> 3;
    const int g    = lane & 7;

    const int n0 = (blockIdx.x * 4 + wvu) * 8;
    if (n0 >= n) return;                      // wave-uniform, no barriers here
    const int nend = min(n0 + 8, n);

    // degrees -> SGPRs (one vector load, 8 readlanes)
    int dvv = 0;
    if (lane < 8 && (n0 + lane) < nend) dvv = deg[n0 + lane];
    int dgf_k[8], dgc_k[8];
#pragma unroll
    for (int k = 0; k < 8; k++) {
        const int d = __builtin_amdgcn_readlane(dvv, k);   // scalar
        dgf_k[k] = d;
        dgc_k[k] = min(d, PAD);
    }

    unsigned int ew[8];
#pragma unroll
    for (int k = 0; k < 8; k++) {
        unsigned int w = (unsigned int)n;                  // sentinel
        if (lane < dgc_k[k]) w = esort[(size_t)(n0 + k) * PAD + lane];
        ew[k] = w;
    }

    const __half2 z2 = __floats2half2_rn(0.f, 0.f);
    __half2 acc[8][4];
#pragma unroll
    for (int k = 0; k < 8; k++) {
        acc[k][0] = z2; acc[k][1] = z2; acc[k][2] = z2; acc[k][3] = z2;
    }

    int mx = 0;
#pragma unroll
    for (int k = 0; k < 8; k++) mx = max(mx, dgc_k[k]);

    const h2x4* tab = (const h2x4*)hh;
    for (int j = 0; j < mx; j += 8) {
#pragma unroll
        for (int k = 0; k < 8; k++) {
            const int dgk = dgc_k[k];                      // scalar
            if (j < dgk) {                                 // uniform skip
                const int s = __shfl((int)ew[k], j + o);   // ds_bpermute
                if (j + o < dgk) {                         // lane predicate
                    const h2x4 v = tab[(size_t)(s * 8 + g)];
                    acc[k][0] = __hadd2(acc[k][0], v.a);
                    acc[k][1] = __hadd2(acc[k][1], v.b);
                    acc[k][2] = __hadd2(acc[k][2], v.c);
                    acc[k][3] = __hadd2(acc[k][3], v.d);
                }
            }
        }
    }

    // rare tail: deg > PAD -> remaining edges in the overflow list.
    int anyovf = 0;
#pragma unroll
    for (int k = 0; k < 8; k++) anyovf |= (int)(dgf_k[k] > PAD);
    if (anyovf) {
        const int cnt = min(*ovf_cnt, OVF_CAP);
#pragma unroll
        for (int k = 0; k < 8; k++) {
            if (dgf_k[k] > PAD) {
                const int nd = n0 + k;
                for (int i2 = 0; i2 < cnt; i2++) {
                    const unsigned long long ev = ovf[i2];
                    if ((int)(ev >> 32) == nd && o == 0) {
                        // octet 0 only: counted once after the xor-reduce
                        const h2x4 v = tab[(size_t)(unsigned int)ev * 8 + g];
                        acc[k][0] = __hadd2(acc[k][0], v.a);
                        acc[k][1] = __hadd2(acc[k][1], v.b);
                        acc[k][2] = __hadd2(acc[k][2], v.c);
                        acc[k][3] = __hadd2(acc[k][3], v.d);
                    }
                }
            }
        }
    }

    // reduce across octets; lane (o,g) owns feature 8g+o; store fp16 mean
#pragma unroll
    for (int k = 0; k < 8; k++) {
        const int nd = n0 + k;
        if (nd < nend) {
            __half2 a0 = acc[k][0], a1 = acc[k][1], a2 = acc[k][2], a3 = acc[k][3];
#pragma unroll
            for (int m = 8; m <= 32; m <<= 1) {
                a0 = __hadd2(a0, h2shfl_xor(a0, m));
                a1 = __hadd2(a1, h2shfl_xor(a1, m));
                a2 = __hadd2(a2, h2shfl_xor(a2, m));
                a3 = __hadd2(a3, h2shfl_xor(a3, m));
            }
            const __half2 sel2 = (o >= 6) ? a3 : (o >= 4) ? a2 : (o >= 2) ? a1 : a0;
            const float hv = (o & 1) ? __high2float(sel2) : __low2float(sel2);
            const float inv = 1.0f / fmaxf((float)dgf_k[k], 1.0f);
            aggh[(size_t)nd * 64 + 8 * g + o] = __float2half(hv * inv);
        }
    }
}

// ---- Phase B standalone: out = PReLU(agg@wl^T + bl + h@wr^T) + x0@wskip^T + bskip
__global__ __launch_bounds__(BLOCK) void dense_kernel(
    const __half* __restrict__ aggh,
    const __half* __restrict__ hh, const float* __restrict__ x0,
    const float* __restrict__ wl, const float* __restrict__ bl,
    const float* __restrict__ wr, const float* __restrict__ wskip,
    const float* __restrict__ bskip, const float* __restrict__ aprelu,
    float* __restrict__ out_f, __half* __restrict__ out_h, int n)
{
    __shared__ float   agg_s[64 * 65];   // fp32; aliased as out staging
    __shared__ __half2 h_s2[64 * 33];
    __shared__ __half2 x_s2[64 * 33];

    const int tid  = threadIdx.x;
    const int lane = tid & 63;
    const int wvu  = __builtin_amdgcn_readfirstlane(tid >> 6);  // 0..7

    const int tileBase = blockIdx.x * 64;
    const __half2 z2 = __floats2half2_rn(0.f, 0.f);

    const __half2* hh2 = (const __half2*)hh;
    const __half2* ag2 = (const __half2*)aggh;
    const float2*  x02 = (const float2*)x0;
    for (int i = tid; i < 64 * 32; i += BLOCK) {
        const int nl = i >> 5, c2 = i & 31;
        const int node = tileBase + nl;
        __half2 hv = z2, xv = z2;
        float2 av = make_float2(0.f, 0.f);
        if (node < n) {
            hv = hh2[(size_t)node * 32 + c2];
            av = __half22float2(ag2[(size_t)node * 32 + c2]);
            const float2 t = x02[(size_t)node * 32 + c2];
            xv = __floats2half2_rn(t.x, t.y);
        }
        h_s2[nl * 33 + c2] = hv;
        x_s2[nl * 33 + c2] = xv;
        agg_s[nl * 65 + 2 * c2]     = av.x;
        agg_s[nl * 65 + 2 * c2 + 1] = av.y;
    }
    __syncthreads();

    float acc1[8], acc2[8], acc3[8];
#pragma unroll
    for (int dd = 0; dd < 8; dd++) { acc1[dd] = 0.f; acc2[dd] = 0.f; acc3[dd] = 0.f; }

    for (int kc = 0; kc < 8; kc++) {
        float ak[8], hk[8], xk[8];
#pragma unroll
        for (int k = 0; k < 8; k++) ak[k] = agg_s[lane * 65 + kc * 8 + k];
        const __half2* hrow = h_s2 + lane * 33 + kc * 4;
        const __half2* xrow = x_s2 + lane * 33 + kc * 4;
#pragma unroll
        for (int k2 = 0; k2 < 4; k2++) {
            const float2 hv = __half22float2(hrow[k2]);
            hk[2 * k2]     = hv.x;
            hk[2 * k2 + 1] = hv.y;
            const float2 xv = __half22float2(xrow[k2]);
            xk[2 * k2]     = xv.x;
            xk[2 * k2 + 1] = xv.y;
        }
#pragma unroll
        for (int dd = 0; dd < 8; dd++) {
            const int d = wvu * 8 + dd;            // wave-uniform -> s_loads
            const float* wlr = wl    + d * 64 + kc * 8;
            const float* wrr = wr    + d * 64 + kc * 8;
            const float* wsr = wskip + d * 64 + kc * 8;
#pragma unroll
            for (int k = 0; k < 8; k++) {
                acc1[dd] += ak[k] * wlr[k];
                acc2[dd] += hk[k] * wrr[k];
                acc3[dd] += xk[k] * wsr[k];
            }
        }
    }
    __syncthreads();   // all waves done reading agg_s before alias-write

    float* out_s = agg_s;
#pragma unroll
    for (int dd = 0; dd < 8; dd++) {
        const int d = wvu * 8 + dd;
        float z = acc1[dd] + acc2[dd] + bl[d];
        z = (z >= 0.f) ? z : aprelu[d] * z;
        out_s[lane * 65 + d] = z + acc3[dd] + bskip[d];
    }
    __syncthreads();

    for (int i = tid; i < 64 * 64; i += BLOCK) {
        const int nl = i >> 6, d = i & 63;
        const int nd = tileBase + nl;
        if (nd < n) {
            const float v = out_s[nl * 65 + d];
            if (out_h) out_h[(size_t)nd * 64 + d] = __float2half(v);
            else       out_f[(size_t)nd * 64 + d] = v;
        }
    }
}

extern "C" void kernel_launch(void* const* d_in, const int* in_sizes, int n_in,
                              void* d_out, int out_size, void* d_ws, size_t ws_size,
                              hipStream_t stream)
{
    const float* x   = (const float*)d_in[0];
    const int*   ei  = (const int*)d_in[1];
    const float* wl0 = (const float*)d_in[2];
    const float* bl0 = (const float*)d_in[3];
    const float* wr0 = (const float*)d_in[4];
    const float* ws0 = (const float*)d_in[5];
    const float* bs0 = (const float*)d_in[6];
    const float* a0  = (const float*)d_in[7];
    const float* wl1 = (const float*)d_in[8];
    const float* bl1 = (const float*)d_in[9];
    const float* wr1 = (const float*)d_in[10];
    const float* ws1 = (const float*)d_in[11];
    const float* bs1 = (const float*)d_in[12];
    const float* a1  = (const float*)d_in[13];

    const int n = in_sizes[0] / 64;
    const int E = in_sizes[1] / 2;
    const int* src = ei;
    const int* dst = ei + E;

    const int NB = (n + 255) >> BSHIFT;   // 391 for n=100000 (<=512)

    // workspace layout:
    int* deg                = (int*)d_ws;                              // n
    int* bcnt               = deg + n;                                 // 512
    int* ovf_cnt            = bcnt + 512;                              // 4
    unsigned long long* ovf = (unsigned long long*)(ovf_cnt + 4);      // OVF_CAP
    unsigned int* esort     = (unsigned int*)(ovf + OVF_CAP);          // n*PAD
    __half* xh              = (__half*)(esort + (size_t)n * PAD);      // (n+1)*64
    __half* h1h             = xh + (size_t)(n + 1) * 64;               // (n+1)*64
    __half* aggh            = h1h + (size_t)(n + 1) * 64;              // n*64
    unsigned int* bucket    = (unsigned int*)h1h;  // ALIAS: dead until dense0
    // NB*BCAP*4 = 391*8000*4 = 12.51MB <= (n+1)*128 = 12.81MB  ✓

    hipMemsetAsync(bcnt, 0, (512 + 4) * sizeof(int), stream);          // bcnt+ovf_cnt
    hipMemsetAsync(xh + (size_t)n * 64, 0, 64 * sizeof(__half), stream);

    cvt_half_kernel<<<1024, 256, 0, stream>>>(
        (const float2*)x, (__half2*)xh, n * 32);

    const int nb1 = (E + P1_CHUNK - 1) / P1_CHUNK;   // 391
    bin_kernel<<<nb1, 256, 0, stream>>>(src, dst, bcnt, bucket, NB, E);
    csr_kernel<<<NB, 256, 0, stream>>>(bcnt, bucket, deg, esort, ovf, ovf_cnt, n);

    // bucket dead; zero h1h sentinel row before layer1 gathers from h1h.
    hipMemsetAsync(h1h + (size_t)n * 64, 0, 64 * sizeof(__half), stream);

    const int ngb    = (n + 31) / 32;     // gather: 4 waves x 8 nodes / block
    const int ntiles = (n + 63) / 64;     // dense tiles

    gather_kernel<<<ngb, 256, 0, stream>>>(deg, esort, ovf, ovf_cnt, xh, aggh, n);
    dense_kernel<<<ntiles, BLOCK, 0, stream>>>(aggh, xh, x,
        wl0, bl0, wr0, ws0, bs0, a0, nullptr, h1h, n);

    gather_kernel<<<ngb, 256, 0, stream>>>(deg, esort, ovf, ovf_cnt, h1h, aggh, n);
    dense_kernel<<<ntiles, BLOCK, 0, stream>>>(aggh, h1h, x,
        wl1, bl1, wr1, ws1, bs1, a1, (float*)d_out, nullptr, n);
}

// Round 4
// 308.053 us; speedup vs baseline: 1.3721x; 1.3721x over previous
//
#include <hip/hip_runtime.h>
#include <hip/hip_fp16.h>

// HeteroGraphSage: 2-layer SAGEConv(mean) + PReLU + input-skip.
// N=100000, IN=D=64, E=1600000, fp32 in/out. Mean degree 16.
// R4: dense phase moved to MFMA. R3 revealed dense_kernel = 95us/layer of
// scalar-VALU matmul (26 TF, VALU 56%, HBM 6%). New dense: zero-LDS,
// zero-barrier, v_mfma_f32_16x16x16f16; wave owns 16 nodes x 64 dims,
// two f32 accumulators (PReLU part / skip part), 48 MFMA per wave.
// Weights pre-packed into per-lane fragment order (pack_w_kernel, 48KB)
// so B-operands are single 8B/lane L1-broadcast loads.
// gather/bin/csr unchanged from R3.

#define BLOCK 512
#define OVF_CAP 8192
#define BSHIFT 8                    // 256 nodes per bucket
#define BCAP 8000
#define PAD 32                      // CSR slots per node

struct alignas(16) h2x4 { __half2 a, b, c, d; };

using f16x4 = __attribute__((ext_vector_type(4))) _Float16;
using f32x4 = __attribute__((ext_vector_type(4))) float;

// ---- build pass 1: bin edges by dst>>8 with per-block LDS histogram.
#define P1_CHUNK 4096
__global__ __launch_bounds__(256) void bin_kernel(
    const int* __restrict__ src, const int* __restrict__ dst,
    int* __restrict__ bcnt, unsigned int* __restrict__ bucket,
    int NB, int E)
{
    __shared__ int cnt[512];
    __shared__ int base[512];
    const int tid = threadIdx.x;
    const int e0  = blockIdx.x * P1_CHUNK;

    for (int i = tid; i < NB; i += 256) cnt[i] = 0;
    __syncthreads();

    int dv[16], sv[16];
#pragma unroll
    for (int u = 0; u < 16; u++) {
        const int e = e0 + u * 256 + tid;
        if (e < E) { dv[u] = dst[e]; sv[u] = src[e]; }
        else       { dv[u] = -1; sv[u] = 0; }
    }
#pragma unroll
    for (int u = 0; u < 16; u++)
        if (dv[u] >= 0) atomicAdd(&cnt[dv[u] >> BSHIFT], 1);
    __syncthreads();

    for (int i = tid; i < NB; i += 256) {
        const int c = cnt[i];
        base[i] = (c > 0) ? atomicAdd(&bcnt[i], c) : 0;
        cnt[i]  = 0;
    }
    __syncthreads();

#pragma unroll
    for (int u = 0; u < 16; u++) {
        if (dv[u] >= 0) {
            const int b = dv[u] >> BSHIFT;
            const int r = atomicAdd(&cnt[b], 1);
            const int pos = base[b] + r;
            if (pos < BCAP)
                bucket[(size_t)b * BCAP + pos] =
                    ((unsigned int)(dv[u] & 255) << 17) | (unsigned int)sv[u];
        }
    }
}

// ---- build pass 2: one block per bucket -> padded CSR + deg.
__global__ __launch_bounds__(256) void csr_kernel(
    const int* __restrict__ bcnt, const unsigned int* __restrict__ bucket,
    int* __restrict__ deg, unsigned int* __restrict__ esort,
    unsigned long long* __restrict__ ovf, int* __restrict__ ovf_cnt, int n)
{
    __shared__ int cnt2[256];
    const int b   = blockIdx.x;
    const int tid = threadIdx.x;
    cnt2[tid] = 0;
    __syncthreads();

    const int m     = min(bcnt[b], BCAP);
    const int nbase = b << BSHIFT;
    for (int i = tid; i < m; i += 256) {
        const unsigned int e = bucket[(size_t)b * BCAP + i];
        const int dloc = (int)(e >> 17);
        const int s    = (int)(e & 0x1FFFF);
        const int r    = atomicAdd(&cnt2[dloc], 1);
        if (r < PAD) {
            esort[(size_t)(nbase + dloc) * PAD + r] = (unsigned int)s;
        } else {
            const int p = atomicAdd(ovf_cnt, 1);
            if (p < OVF_CAP)
                ovf[p] = ((unsigned long long)(unsigned int)(nbase + dloc) << 32)
                       | (unsigned long long)(unsigned int)s;
        }
    }
    __syncthreads();
    const int node = nbase + tid;
    if (node < n) deg[node] = cnt2[tid];
}

// fp32 -> fp16 table (m = count of float2 pairs)
__global__ __launch_bounds__(256) void cvt_half_kernel(
    const float2* __restrict__ in, __half2* __restrict__ out, int m)
{
    int i = blockIdx.x * blockDim.x + threadIdx.x;
    int stride = gridDim.x * blockDim.x;
    for (; i < m; i += stride) {
        float2 v = in[i];
        out[i] = __floats2half2_rn(v.x, v.y);
    }
}

// ---- weight pre-pack: per-lane MFMA B-fragments for both layers.
// frag f = wsel*16 + kb*4 + ct  (wsel: 0=wl 1=wr 2=wskip; kb: K/16; ct: col/16)
// elem (f, lane, j): B[k][col] = W[col][k], k = kb*16 + (lane>>4)*4 + j,
// col = ct*16 + (lane&15).  bp[layer][f*256 + lane*4 + j].
__global__ __launch_bounds__(256) void pack_w_kernel(
    const float* __restrict__ wl0, const float* __restrict__ wr0,
    const float* __restrict__ ws0, const float* __restrict__ wl1,
    const float* __restrict__ wr1, const float* __restrict__ ws1,
    __half* __restrict__ bp)
{
    const int t = blockIdx.x * 256 + threadIdx.x;
    if (t >= 2 * 48 * 256) return;
    const int layer = t / (48 * 256);
    const int rem   = t % (48 * 256);
    const int f     = rem >> 8;
    const int lane  = (rem >> 2) & 63;
    const int j     = rem & 3;
    const int wsel  = f >> 4;
    const int kb    = (f >> 2) & 3;
    const int ct    = f & 3;
    const int k     = kb * 16 + (lane >> 4) * 4 + j;
    const int col   = ct * 16 + (lane & 15);
    const float* W  = (layer == 0)
        ? ((wsel == 0) ? wl0 : (wsel == 1) ? wr0 : ws0)
        : ((wsel == 0) ? wl1 : (wsel == 1) ? wr1 : ws1);
    bp[t] = __float2half(W[col * 64 + k]);
}

static __device__ inline __half2 h2shfl_xor(__half2 v, int mask) {
    union { __half2 h; int i; } u; u.h = v;
    u.i = __shfl_xor(u.i, mask);
    return u.h;
}

// ---- Phase A standalone: mean-aggregate neighbors -> aggh (fp16).
__global__ __launch_bounds__(256, 6) void gather_kernel(
    const int* __restrict__ deg, const unsigned int* __restrict__ esort,
    const unsigned long long* __restrict__ ovf, const int* __restrict__ ovf_cnt,
    const __half* __restrict__ hh, __half* __restrict__ aggh, int n)
{
    const int tid  = threadIdx.x;
    const int lane = tid & 63;
    const int wvu  = tid >> 6;    // 0..3
    const int o    = lane >> 3;
    const int g    = lane & 7;

    const int n0 = (blockIdx.x * 4 + wvu) * 8;
    if (n0 >= n) return;
    const int nend = min(n0 + 8, n);

    int dvv = 0;
    if (lane < 8 && (n0 + lane) < nend) dvv = deg[n0 + lane];
    int dgf_k[8], dgc_k[8];
#pragma unroll
    for (int k = 0; k < 8; k++) {
        const int d = __builtin_amdgcn_readlane(dvv, k);   // scalar
        dgf_k[k] = d;
        dgc_k[k] = min(d, PAD);
    }

    unsigned int ew[8];
#pragma unroll
    for (int k = 0; k < 8; k++) {
        unsigned int w = (unsigned int)n;                  // sentinel
        if (lane < dgc_k[k]) w = esort[(size_t)(n0 + k) * PAD + lane];
        ew[k] = w;
    }

    const __half2 z2 = __floats2half2_rn(0.f, 0.f);
    __half2 acc[8][4];
#pragma unroll
    for (int k = 0; k < 8; k++) {
        acc[k][0] = z2; acc[k][1] = z2; acc[k][2] = z2; acc[k][3] = z2;
    }

    int mx = 0;
#pragma unroll
    for (int k = 0; k < 8; k++) mx = max(mx, dgc_k[k]);

    const h2x4* tab = (const h2x4*)hh;
    for (int j = 0; j < mx; j += 8) {
#pragma unroll
        for (int k = 0; k < 8; k++) {
            const int dgk = dgc_k[k];
            if (j < dgk) {
                const int s = __shfl((int)ew[k], j + o);
                if (j + o < dgk) {
                    const h2x4 v = tab[(size_t)(s * 8 + g)];
                    acc[k][0] = __hadd2(acc[k][0], v.a);
                    acc[k][1] = __hadd2(acc[k][1], v.b);
                    acc[k][2] = __hadd2(acc[k][2], v.c);
                    acc[k][3] = __hadd2(acc[k][3], v.d);
                }
            }
        }
    }

    int anyovf = 0;
#pragma unroll
    for (int k = 0; k < 8; k++) anyovf |= (int)(dgf_k[k] > PAD);
    if (anyovf) {
        const int cnt = min(*ovf_cnt, OVF_CAP);
#pragma unroll
        for (int k = 0; k < 8; k++) {
            if (dgf_k[k] > PAD) {
                const int nd = n0 + k;
                for (int i2 = 0; i2 < cnt; i2++) {
                    const unsigned long long ev = ovf[i2];
                    if ((int)(ev >> 32) == nd && o == 0) {
                        const h2x4 v = tab[(size_t)(unsigned int)ev * 8 + g];
                        acc[k][0] = __hadd2(acc[k][0], v.a);
                        acc[k][1] = __hadd2(acc[k][1], v.b);
                        acc[k][2] = __hadd2(acc[k][2], v.c);
                        acc[k][3] = __hadd2(acc[k][3], v.d);
                    }
                }
            }
        }
    }

#pragma unroll
    for (int k = 0; k < 8; k++) {
        const int nd = n0 + k;
        if (nd < nend) {
            __half2 a0 = acc[k][0], a1 = acc[k][1], a2 = acc[k][2], a3 = acc[k][3];
#pragma unroll
            for (int m = 8; m <= 32; m <<= 1) {
                a0 = __hadd2(a0, h2shfl_xor(a0, m));
                a1 = __hadd2(a1, h2shfl_xor(a1, m));
                a2 = __hadd2(a2, h2shfl_xor(a2, m));
                a3 = __hadd2(a3, h2shfl_xor(a3, m));
            }
            const __half2 sel2 = (o >= 6) ? a3 : (o >= 4) ? a2 : (o >= 2) ? a1 : a0;
            const float hv = (o & 1) ? __high2float(sel2) : __low2float(sel2);
            const float inv = 1.0f / fmaxf((float)dgf_k[k], 1.0f);
            aggh[(size_t)nd * 64 + 8 * g + o] = __float2half(hv * inv);
        }
    }
}

// ---- Phase B: MFMA dense. Wave owns 16 nodes x 64 dims; zero LDS/barriers.
// out = PReLU(agg@wl^T + bl + h@wr^T, a) + x@wskip^T + bskip
__global__ __launch_bounds__(256) void dense_kernel(
    const __half* __restrict__ aggh, const __half* __restrict__ hh,
    const __half* __restrict__ xh, const __half* __restrict__ bpack,
    const float* __restrict__ bl, const float* __restrict__ aprelu,
    const float* __restrict__ bskip,
    float* __restrict__ out_f, __half* __restrict__ out_h, int n)
{
    const int tid  = threadIdx.x;
    const int lane = tid & 63;
    const int wvu  = tid >> 6;                 // 0..3
    const int m0   = blockIdx.x * 64 + wvu * 16;
    if (m0 >= n) return;

    const int row  = lane & 15;                // A row within tile
    const int koff = (lane >> 4) * 4;          // A k offset within 16-block
    const int node = m0 + row;
    const bool valid = node < n;

    // A fragments: 4 K-blocks x {agg, h, x}, 8B/lane contiguous loads
    f16x4 a_ag[4], a_h[4], a_x[4];
#pragma unroll
    for (int kb = 0; kb < 4; kb++) {
        const size_t off = (size_t)node * 64 + kb * 16 + koff;
        f16x4 z = {};
        a_ag[kb] = valid ? *(const f16x4*)(aggh + off) : z;
        a_h[kb]  = valid ? *(const f16x4*)(hh + off)   : z;
        a_x[kb]  = valid ? *(const f16x4*)(xh + off)   : z;
    }

    const f16x4* bp = (const f16x4*)bpack;     // [f][lane] -> f*64 + lane
    f32x4 acc1[4], acc2[4];
#pragma unroll
    for (int ct = 0; ct < 4; ct++) {
        acc1[ct] = (f32x4)(0.f);
        acc2[ct] = (f32x4)(0.f);
    }

#pragma unroll
    for (int ct = 0; ct < 4; ct++) {
#pragma unroll
        for (int kb = 0; kb < 4; kb++) {
            const f16x4 b_wl = bp[(0 * 16 + kb * 4 + ct) * 64 + lane];
            acc1[ct] = __builtin_amdgcn_mfma_f32_16x16x16f16(
                a_ag[kb], b_wl, acc1[ct], 0, 0, 0);
            const f16x4 b_wr = bp[(1 * 16 + kb * 4 + ct) * 64 + lane];
            acc1[ct] = __builtin_amdgcn_mfma_f32_16x16x16f16(
                a_h[kb], b_wr, acc1[ct], 0, 0, 0);
            const f16x4 b_ws = bp[(2 * 16 + kb * 4 + ct) * 64 + lane];
            acc2[ct] = __builtin_amdgcn_mfma_f32_16x16x16f16(
                a_x[kb], b_ws, acc2[ct], 0, 0, 0);
        }
    }

    // epilogue: D[row][col] in lane (row>>2)*16 + col, reg row&3
#pragma unroll
    for (int ct = 0; ct < 4; ct++) {
        const int col = ct * 16 + (lane & 15);
        const float blv = bl[col];
        const float av  = aprelu[col];
        const float bsv = bskip[col];
#pragma unroll
        for (int r = 0; r < 4; r++) {
            const int nd = m0 + (lane >> 4) * 4 + r;
            if (nd < n) {
                float z = acc1[ct][r] + blv;
                z = (z >= 0.f) ? z : av * z;
                const float v = z + acc2[ct][r] + bsv;
                if (out_h) out_h[(size_t)nd * 64 + col] = __float2half(v);
                else       out_f[(size_t)nd * 64 + col] = v;
            }
        }
    }
}

extern "C" void kernel_launch(void* const* d_in, const int* in_sizes, int n_in,
                              void* d_out, int out_size, void* d_ws, size_t ws_size,
                              hipStream_t stream)
{
    const float* x   = (const float*)d_in[0];
    const int*   ei  = (const int*)d_in[1];
    const float* wl0 = (const float*)d_in[2];
    const float* bl0 = (const float*)d_in[3];
    const float* wr0 = (const float*)d_in[4];
    const float* ws0 = (const float*)d_in[5];
    const float* bs0 = (const float*)d_in[6];
    const float* a0  = (const float*)d_in[7];
    const float* wl1 = (const float*)d_in[8];
    const float* bl1 = (const float*)d_in[9];
    const float* wr1 = (const float*)d_in[10];
    const float* ws1 = (const float*)d_in[11];
    const float* bs1 = (const float*)d_in[12];
    const float* a1  = (const float*)d_in[13];

    const int n = in_sizes[0] / 64;
    const int E = in_sizes[1] / 2;
    const int* src = ei;
    const int* dst = ei + E;

    const int NB = (n + 255) >> BSHIFT;   // 391 for n=100000 (<=512)

    // workspace layout:
    int* deg                = (int*)d_ws;                              // n
    int* bcnt               = deg + n;                                 // 512
    int* ovf_cnt            = bcnt + 512;                              // 4
    unsigned long long* ovf = (unsigned long long*)(ovf_cnt + 4);      // OVF_CAP
    unsigned int* esort     = (unsigned int*)(ovf + OVF_CAP);          // n*PAD
    __half* xh              = (__half*)(esort + (size_t)n * PAD);      // (n+1)*64
    __half* h1h             = xh + (size_t)(n + 1) * 64;               // (n+1)*64
    __half* aggh            = h1h + (size_t)(n + 1) * 64;              // n*64
    __half* bpack           = aggh + (size_t)n * 64;                   // 2*48*256
    unsigned int* bucket    = (unsigned int*)h1h;  // ALIAS: dead until dense0
    // NB*BCAP*4 = 391*8000*4 = 12.51MB <= (n+1)*128 = 12.81MB  ✓

    hipMemsetAsync(bcnt, 0, (512 + 4) * sizeof(int), stream);          // bcnt+ovf_cnt
    hipMemsetAsync(xh + (size_t)n * 64, 0, 64 * sizeof(__half), stream);

    cvt_half_kernel<<<1024, 256, 0, stream>>>(
        (const float2*)x, (__half2*)xh, n * 32);
    pack_w_kernel<<<96, 256, 0, stream>>>(wl0, wr0, ws0, wl1, wr1, ws1, bpack);

    const int nb1 = (E + P1_CHUNK - 1) / P1_CHUNK;   // 391
    bin_kernel<<<nb1, 256, 0, stream>>>(src, dst, bcnt, bucket, NB, E);
    csr_kernel<<<NB, 256, 0, stream>>>(bcnt, bucket, deg, esort, ovf, ovf_cnt, n);

    // bucket dead; zero h1h sentinel row before layer1 gathers from h1h.
    hipMemsetAsync(h1h + (size_t)n * 64, 0, 64 * sizeof(__half), stream);

    const int ngb    = (n + 31) / 32;     // gather: 4 waves x 8 nodes / block
    const int ntiles = (n + 63) / 64;     // dense tiles

    gather_kernel<<<ngb, 256, 0, stream>>>(deg, esort, ovf, ovf_cnt, xh, aggh, n);
    dense_kernel<<<ntiles, 256, 0, stream>>>(aggh, xh, xh, bpack,
        bl0, a0, bs0, nullptr, h1h, n);

    gather_kernel<<<ngb, 256, 0, stream>>>(deg, esort, ovf, ovf_cnt, h1h, aggh, n);
    dense_kernel<<<ntiles, 256, 0, stream>>>(aggh, h1h, xh, bpack + 48 * 256,
        bl1, a1, bs1, (float*)d_out, nullptr, n);
}